// Round 1
// baseline (470.113 us; speedup 1.0000x reference)
//
#include <hip/hip_runtime.h>

#define IN_DIM 128
#define HEADS 4
#define OUT_DIM 32
#define NEG 0.2f

// ---------------- projection: feat = x @ W, el/er = per-head attn dots ----
// Block = 256 threads = 4 waves. Each block: 64 nodes x 128 outputs.
// Wave w (= head h) computes columns [32h, 32h+32) for all 64 nodes;
// lane n owns node (block_n0 + n), 32 accumulators in registers.
// W is read with wave-uniform addresses -> s_load (scalar cache), so the
// inner loop is 1 ds_read_b32 + 32 v_fmac -> VALU-bound.
__global__ __launch_bounds__(256) void proj_kernel(
    const float* __restrict__ x, const float* __restrict__ fc_w,
    const float* __restrict__ attn_l, const float* __restrict__ attn_r,
    float* __restrict__ feat, float* __restrict__ el, float* __restrict__ er,
    int N)
{
    __shared__ float xs[128 * 65];   // [i][n] transposed, padded (conflict-free)
    const int tid = threadIdx.x;
    const int n0 = blockIdx.x * 64;

    // stage x tile (64 nodes x 128 features), coalesced read, padded store
    #pragma unroll
    for (int rep = 0; rep < 32; ++rep) {
        int idx = rep * 256 + tid;
        int n = idx >> 7, i = idx & 127;
        int gn = n0 + n;
        float v = (gn < N) ? x[(size_t)gn * 128 + i] : 0.f;
        xs[i * 65 + n] = v;
    }
    __syncthreads();

    const int wave = __builtin_amdgcn_readfirstlane(tid >> 6);  // == head h
    const int lane = tid & 63;
    const int k0 = wave * 32;

    float acc[32];
    #pragma unroll
    for (int d = 0; d < 32; ++d) acc[d] = 0.f;

    for (int i = 0; i < 128; ++i) {
        float xv = xs[i * 65 + lane];
        const float* wr = fc_w + i * 128 + k0;   // wave-uniform -> s_load
        #pragma unroll
        for (int d = 0; d < 32; ++d) acc[d] = fmaf(xv, wr[d], acc[d]);
    }

    const int gn = n0 + lane;
    if (gn < N) {
        float* fp = feat + (size_t)gn * 128 + k0;
        #pragma unroll
        for (int d4 = 0; d4 < 8; ++d4) {
            float4 v4 = make_float4(acc[d4*4], acc[d4*4+1], acc[d4*4+2], acc[d4*4+3]);
            *(float4*)(fp + d4 * 4) = v4;
        }
        float sl = 0.f, sr = 0.f;
        const float* al = attn_l + k0;           // wave-uniform -> s_load
        const float* ar = attn_r + k0;
        #pragma unroll
        for (int d = 0; d < 32; ++d) {
            sl = fmaf(acc[d], al[d], sl);
            sr = fmaf(acc[d], ar[d], sr);
        }
        el[gn * 4 + wave] = sl;
        er[gn * 4 + wave] = sr;
    }
}

// ---------------- CSR build ----------------------------------------------
__global__ void hist_kernel(const int* __restrict__ edst, int* __restrict__ deg, int E)
{
    int i = blockIdx.x * 256 + threadIdx.x;
    if (i < E) atomicAdd(&deg[edst[i]], 1);
}

// single-block exclusive scan over deg[N]; writes row_start[N+1] and cursor[N]
__global__ __launch_bounds__(1024) void scan_kernel(
    const int* __restrict__ deg, int* __restrict__ row_start,
    int* __restrict__ cursor, int N)
{
    __shared__ int part[1024];
    const int t = threadIdx.x;
    const int CH = (N + 1023) >> 10;
    const int s0 = t * CH;
    const int s1 = min(s0 + CH, N);

    int sum = 0;
    #pragma unroll 4
    for (int i = s0; i < s1; ++i) sum += deg[i];
    part[t] = sum;
    __syncthreads();

    // Hillis-Steele inclusive scan over 1024 partials
    for (int off = 1; off < 1024; off <<= 1) {
        int v = (t >= off) ? part[t - off] : 0;
        __syncthreads();
        part[t] += v;
        __syncthreads();
    }

    int run = (t == 0) ? 0 : part[t - 1];
    #pragma unroll 4
    for (int i = s0; i < s1; ++i) {
        row_start[i] = run;
        cursor[i]    = run;
        run += deg[i];
    }
    if (t == 1023) row_start[N] = part[1023];
}

__global__ void scatter_kernel(const int* __restrict__ esrc, const int* __restrict__ edst,
                               int* __restrict__ cursor, int* __restrict__ csr, int E)
{
    int i = blockIdx.x * 256 + threadIdx.x;
    if (i < E) {
        int d = edst[i];
        int pos = atomicAdd(&cursor[d], 1);
        csr[pos] = esrc[i];
    }
}

// ---------------- aggregation: one wave per destination node --------------
// lane t: head h = t>>4, feature pair d = 2*(t&15). Accumulates
// unnormalized sum(exp(e)*feat) and sum(exp(e)) in registers (softmax
// without max-subtraction: e <= ~8, exp fits f32 easily), divides once,
// then head-means via shfl_xor(16)+shfl_xor(32).
__global__ __launch_bounds__(256) void aggregate_kernel(
    const float* __restrict__ feat, const float* __restrict__ el,
    const float* __restrict__ er, const int* __restrict__ row_start,
    const int* __restrict__ csr, const float* __restrict__ bias,
    float* __restrict__ out, int N)
{
    int node = blockIdx.x * 4 + (threadIdx.x >> 6);
    node = __builtin_amdgcn_readfirstlane(node);
    if (node >= N) return;
    const int lane = threadIdx.x & 63;
    const int h = lane >> 4;

    const float er_vh = er[node * 4 + h];
    const int start = row_start[node];
    const int end   = row_start[node + 1];

    float acc0 = 0.f, acc1 = 0.f, s = 0.f;
    const float2* f2 = (const float2*)feat;
    for (int idx = start; idx < end; ++idx) {
        int u = csr[idx];                        // uniform -> scalar load
        float e = el[u * 4 + h] + er_vh;
        e = (e > 0.f) ? e : NEG * e;
        float ex = __expf(e);
        float2 f = f2[(size_t)u * 64 + lane];    // 512B coalesced gather
        acc0 = fmaf(ex, f.x, acc0);
        acc1 = fmaf(ex, f.y, acc1);
        s += ex;
    }
    s = fmaxf(s, 1e-16f);
    float r0 = acc0 / s, r1 = acc1 / s;
    r0 += __shfl_xor(r0, 16); r0 += __shfl_xor(r0, 32);
    r1 += __shfl_xor(r1, 16); r1 += __shfl_xor(r1, 32);

    if (lane < 16) {
        int d0 = lane * 2;
        float bm0 = 0.25f * (bias[d0]     + bias[32 + d0] + bias[64 + d0] + bias[96 + d0]);
        float bm1 = 0.25f * (bias[d0 + 1] + bias[33 + d0] + bias[65 + d0] + bias[97 + d0]);
        float2 o;
        o.x = 0.25f * r0 + bm0;
        o.y = 0.25f * r1 + bm1;
        ((float2*)out)[(size_t)node * 16 + lane] = o;
    }
}

// ---------------- launch --------------------------------------------------
extern "C" void kernel_launch(void* const* d_in, const int* in_sizes, int n_in,
                              void* d_out, int out_size, void* d_ws, size_t ws_size,
                              hipStream_t stream)
{
    const float* x      = (const float*)d_in[0];
    const int*   esrc   = (const int*)  d_in[1];
    const int*   edst   = (const int*)  d_in[2];
    const float* fc_w   = (const float*)d_in[3];
    const float* attn_l = (const float*)d_in[4];
    const float* attn_r = (const float*)d_in[5];
    const float* bias   = (const float*)d_in[6];
    float* out = (float*)d_out;

    const int N = in_sizes[0] / IN_DIM;   // 100000
    const int E = in_sizes[1];            // 1600000

    // workspace carve (total ~62 MB)
    size_t o = 0;
    char* base = (char*)d_ws;
    auto alloc = [&](size_t bytes) -> void* {
        void* p = base + o;
        o += (bytes + 255) & ~(size_t)255;
        return p;
    };
    float* feat      = (float*)alloc((size_t)N * 128 * sizeof(float));
    float* el        = (float*)alloc((size_t)N * 4 * sizeof(float));
    float* er        = (float*)alloc((size_t)N * 4 * sizeof(float));
    int*   deg       = (int*)  alloc((size_t)N * sizeof(int));
    int*   row_start = (int*)  alloc(((size_t)N + 1) * sizeof(int));
    int*   cursor    = (int*)  alloc((size_t)N * sizeof(int));
    int*   csr       = (int*)  alloc((size_t)E * sizeof(int));
    (void)ws_size;

    hipMemsetAsync(deg, 0, (size_t)N * sizeof(int), stream);

    proj_kernel<<<(N + 63) / 64, 256, 0, stream>>>(x, fc_w, attn_l, attn_r,
                                                   feat, el, er, N);
    hist_kernel<<<(E + 255) / 256, 256, 0, stream>>>(edst, deg, E);
    scan_kernel<<<1, 1024, 0, stream>>>(deg, row_start, cursor, N);
    scatter_kernel<<<(E + 255) / 256, 256, 0, stream>>>(esrc, edst, cursor, csr, E);
    aggregate_kernel<<<(N + 3) / 4, 256, 0, stream>>>(feat, el, er, row_start,
                                                      csr, bias, out, N);
}

// Round 2
// 408.308 us; speedup vs baseline: 1.1514x; 1.1514x over previous
//
#include <hip/hip_runtime.h>

#define IN_DIM 128
#define HEADS 4
#define OUT_DIM 32
#define NEG 0.2f

typedef unsigned int uint;

__device__ __forceinline__ uint bf16r(float f) {
    uint u = __float_as_uint(f);
    return (u + 0x7fffu + ((u >> 16) & 1u)) >> 16;   // RNE
}

// ---------------- projection: feat_b(bf16) = x @ W, el/er attn dots -------
// Block = 256 = 4 waves; 64 nodes x 128 outputs per block. Wave w (=head h)
// computes columns [32w,32w+32); W rows read wave-uniform -> s_load.
__global__ __launch_bounds__(256) void proj_kernel(
    const float* __restrict__ x, const float* __restrict__ fc_w,
    const float* __restrict__ attn_l, const float* __restrict__ attn_r,
    uint* __restrict__ feat_b, float* __restrict__ el, float* __restrict__ er,
    int N)
{
    __shared__ float xs[128 * 65];   // [i][n] transposed, padded
    const int tid = threadIdx.x;
    const int n0 = blockIdx.x * 64;

    #pragma unroll
    for (int rep = 0; rep < 32; ++rep) {
        int idx = rep * 256 + tid;
        int n = idx >> 7, i = idx & 127;
        int gn = n0 + n;
        float v = (gn < N) ? x[(size_t)gn * 128 + i] : 0.f;
        xs[i * 65 + n] = v;
    }
    __syncthreads();

    const int wave = __builtin_amdgcn_readfirstlane(tid >> 6);  // == head
    const int lane = tid & 63;
    const int k0 = wave * 32;

    float acc[32];
    #pragma unroll
    for (int d = 0; d < 32; ++d) acc[d] = 0.f;

    for (int i = 0; i < 128; ++i) {
        float xv = xs[i * 65 + lane];
        const float* wr = fc_w + i * 128 + k0;   // wave-uniform -> s_load
        #pragma unroll
        for (int d = 0; d < 32; ++d) acc[d] = fmaf(xv, wr[d], acc[d]);
    }

    const int gn = n0 + lane;
    if (gn < N) {
        // pack 32 f32 -> 16 bf16-pairs, store as 4x uint4
        uint* fp = feat_b + (size_t)gn * 64 + wave * 16;
        #pragma unroll
        for (int q = 0; q < 4; ++q) {
            uint4 v;
            v.x = bf16r(acc[q*8+0]) | (bf16r(acc[q*8+1]) << 16);
            v.y = bf16r(acc[q*8+2]) | (bf16r(acc[q*8+3]) << 16);
            v.z = bf16r(acc[q*8+4]) | (bf16r(acc[q*8+5]) << 16);
            v.w = bf16r(acc[q*8+6]) | (bf16r(acc[q*8+7]) << 16);
            *(uint4*)(fp + q * 4) = v;
        }
        float sl = 0.f, sr = 0.f;
        const float* al = attn_l + k0;           // wave-uniform -> s_load
        const float* ar = attn_r + k0;
        #pragma unroll
        for (int d = 0; d < 32; ++d) {
            sl = fmaf(acc[d], al[d], sl);
            sr = fmaf(acc[d], ar[d], sr);
        }
        el[gn * 4 + wave] = sl;
        er[gn * 4 + wave] = sr;
    }
}

// ---------------- CSR build ----------------------------------------------
__global__ void hist_kernel(const int4* __restrict__ edst4, int* __restrict__ deg, int E4)
{
    int i = blockIdx.x * 256 + threadIdx.x;
    if (i < E4) {
        int4 d = edst4[i];
        atomicAdd(&deg[d.x], 1);
        atomicAdd(&deg[d.y], 1);
        atomicAdd(&deg[d.z], 1);
        atomicAdd(&deg[d.w], 1);
    }
}

// block sums over 1024-element chunks (int4 coalesced)
__global__ __launch_bounds__(256) void scan_part_kernel(
    const int* __restrict__ deg, int* __restrict__ blockSums, int N)
{
    __shared__ int red[256];
    const int t = threadIdx.x;
    const int i0 = blockIdx.x * 1024 + t * 4;
    int s = 0;
    if (i0 + 3 < N) {
        int4 d = *(const int4*)(deg + i0);
        s = d.x + d.y + d.z + d.w;
    } else {
        for (int k = 0; k < 4; ++k) if (i0 + k < N) s += deg[i0 + k];
    }
    red[t] = s;
    __syncthreads();
    for (int st = 128; st > 0; st >>= 1) {
        if (t < st) red[t] += red[t + st];
        __syncthreads();
    }
    if (t == 0) blockSums[blockIdx.x] = red[0];
}

// scan the (<=128) block sums; write exclusive offsets + row_start[N]=total
__global__ __launch_bounds__(128) void scan_small_kernel(
    const int* __restrict__ blockSums, int* __restrict__ blockOff,
    int* __restrict__ row_start, int nblk, int N)
{
    __shared__ int part[128];
    const int t = threadIdx.x;
    int v = (t < nblk) ? blockSums[t] : 0;
    part[t] = v;
    __syncthreads();
    for (int off = 1; off < 128; off <<= 1) {
        int u = (t >= off) ? part[t - off] : 0;
        __syncthreads();
        part[t] += u;
        __syncthreads();
    }
    if (t < nblk) blockOff[t] = part[t] - v;     // exclusive
    if (t == 127) row_start[N] = part[127];      // total == E
}

// final: per-block prefix, write row_start + cursor (int4 coalesced)
__global__ __launch_bounds__(256) void scan_final_kernel(
    const int* __restrict__ deg, const int* __restrict__ blockOff,
    int* __restrict__ row_start, int* __restrict__ cursor, int N)
{
    __shared__ int sums[256];
    const int t = threadIdx.x;
    const int i0 = blockIdx.x * 1024 + t * 4;
    int d0 = 0, d1 = 0, d2 = 0, d3 = 0;
    if (i0 + 3 < N) {
        int4 d = *(const int4*)(deg + i0);
        d0 = d.x; d1 = d.y; d2 = d.z; d3 = d.w;
    } else {
        if (i0     < N) d0 = deg[i0];
        if (i0 + 1 < N) d1 = deg[i0 + 1];
        if (i0 + 2 < N) d2 = deg[i0 + 2];
    }
    int tsum = d0 + d1 + d2 + d3;
    sums[t] = tsum;
    __syncthreads();
    for (int off = 1; off < 256; off <<= 1) {
        int u = (t >= off) ? sums[t - off] : 0;
        __syncthreads();
        sums[t] += u;
        __syncthreads();
    }
    int run = blockOff[blockIdx.x] + sums[t] - tsum;
    if (i0 + 3 < N) {
        int4 r;
        r.x = run; r.y = run + d0; r.z = run + d0 + d1; r.w = run + d0 + d1 + d2;
        *(int4*)(row_start + i0) = r;
        *(int4*)(cursor + i0)    = r;
    } else {
        int rr = run;
        if (i0     < N) { row_start[i0]   = rr; cursor[i0]   = rr; rr += d0; }
        if (i0 + 1 < N) { row_start[i0+1] = rr; cursor[i0+1] = rr; rr += d1; }
        if (i0 + 2 < N) { row_start[i0+2] = rr; cursor[i0+2] = rr; }
    }
}

__global__ void scatter_kernel(const int4* __restrict__ esrc4, const int4* __restrict__ edst4,
                               int* __restrict__ cursor, int* __restrict__ csr, int E4)
{
    int i = blockIdx.x * 256 + threadIdx.x;
    if (i < E4) {
        int4 s = esrc4[i];
        int4 d = edst4[i];
        csr[atomicAdd(&cursor[d.x], 1)] = s.x;
        csr[atomicAdd(&cursor[d.y], 1)] = s.y;
        csr[atomicAdd(&cursor[d.z], 1)] = s.z;
        csr[atomicAdd(&cursor[d.w], 1)] = s.w;
    }
}

// ---------------- aggregation: one wave per destination node --------------
// lane: head h = lane>>4, features (2*lane, 2*lane+1) packed in one uint.
// Unnormalized online softmax (e <= ~8 so exp fits f32), divide once,
// head-mean via shfl_xor(16)+shfl_xor(32).
__global__ __launch_bounds__(256) void aggregate_kernel(
    const uint* __restrict__ feat_b, const float* __restrict__ el,
    const float* __restrict__ er, const int* __restrict__ row_start,
    const int* __restrict__ csr, const float* __restrict__ bias,
    float* __restrict__ out, int N)
{
    int node = blockIdx.x * 4 + (threadIdx.x >> 6);
    node = __builtin_amdgcn_readfirstlane(node);
    if (node >= N) return;
    const int lane = threadIdx.x & 63;
    const int h = lane >> 4;

    const float er_vh = er[node * 4 + h];
    const int start = row_start[node];
    const int end   = row_start[node + 1];

    float acc0 = 0.f, acc1 = 0.f, s = 0.f;
    int u = (start < end) ? csr[start] : 0;
    for (int idx = start; idx < end; ++idx) {
        int u2 = (idx + 1 < end) ? csr[idx + 1] : 0;   // prefetch next
        float e = el[u * 4 + h] + er_vh;
        e = (e > 0.f) ? e : NEG * e;
        float ex = __expf(e);
        uint p = feat_b[(size_t)u * 64 + lane];        // 256B coalesced gather
        float lo = __uint_as_float(p << 16);
        float hi = __uint_as_float(p & 0xffff0000u);
        acc0 = fmaf(ex, lo, acc0);
        acc1 = fmaf(ex, hi, acc1);
        s += ex;
        u = u2;
    }
    s = fmaxf(s, 1e-16f);
    float r0 = acc0 / s, r1 = acc1 / s;
    r0 += __shfl_xor(r0, 16); r0 += __shfl_xor(r0, 32);
    r1 += __shfl_xor(r1, 16); r1 += __shfl_xor(r1, 32);

    if (lane < 16) {
        int d0 = lane * 2;
        float bm0 = 0.25f * (bias[d0]     + bias[32 + d0] + bias[64 + d0] + bias[96 + d0]);
        float bm1 = 0.25f * (bias[d0 + 1] + bias[33 + d0] + bias[65 + d0] + bias[97 + d0]);
        float2 o;
        o.x = 0.25f * r0 + bm0;
        o.y = 0.25f * r1 + bm1;
        ((float2*)out)[(size_t)node * 16 + lane] = o;
    }
}

// ---------------- launch --------------------------------------------------
extern "C" void kernel_launch(void* const* d_in, const int* in_sizes, int n_in,
                              void* d_out, int out_size, void* d_ws, size_t ws_size,
                              hipStream_t stream)
{
    const float* x      = (const float*)d_in[0];
    const int*   esrc   = (const int*)  d_in[1];
    const int*   edst   = (const int*)  d_in[2];
    const float* fc_w   = (const float*)d_in[3];
    const float* attn_l = (const float*)d_in[4];
    const float* attn_r = (const float*)d_in[5];
    const float* bias   = (const float*)d_in[6];
    float* out = (float*)d_out;

    const int N = in_sizes[0] / IN_DIM;   // 100000
    const int E = in_sizes[1];            // 1600000

    size_t o = 0;
    char* base = (char*)d_ws;
    auto alloc = [&](size_t bytes) -> void* {
        void* p = base + o;
        o += (bytes + 255) & ~(size_t)255;
        return p;
    };
    uint*  feat_b    = (uint*) alloc((size_t)N * 64 * sizeof(uint));   // bf16 packed
    float* el        = (float*)alloc((size_t)N * 4 * sizeof(float));
    float* er        = (float*)alloc((size_t)N * 4 * sizeof(float));
    int*   deg       = (int*)  alloc((size_t)N * sizeof(int));
    int*   row_start = (int*)  alloc(((size_t)N + 1) * sizeof(int));
    int*   cursor    = (int*)  alloc((size_t)N * sizeof(int));
    int*   csr       = (int*)  alloc((size_t)E * sizeof(int));
    int*   blockSums = (int*)  alloc(128 * sizeof(int));
    int*   blockOff  = (int*)  alloc(128 * sizeof(int));
    (void)ws_size;

    const int nblkScan = (N + 1023) / 1024;   // 98

    hipMemsetAsync(deg, 0, (size_t)N * sizeof(int), stream);

    proj_kernel<<<(N + 63) / 64, 256, 0, stream>>>(x, fc_w, attn_l, attn_r,
                                                   feat_b, el, er, N);
    hist_kernel<<<(E / 4 + 255) / 256, 256, 0, stream>>>((const int4*)edst, deg, E / 4);
    scan_part_kernel<<<nblkScan, 256, 0, stream>>>(deg, blockSums, N);
    scan_small_kernel<<<1, 128, 0, stream>>>(blockSums, blockOff, row_start, nblkScan, N);
    scan_final_kernel<<<nblkScan, 256, 0, stream>>>(deg, blockOff, row_start, cursor, N);
    scatter_kernel<<<(E / 4 + 255) / 256, 256, 0, stream>>>((const int4*)esrc, (const int4*)edst,
                                                            cursor, csr, E / 4);
    aggregate_kernel<<<(N + 3) / 4, 256, 0, stream>>>(feat_b, el, er, row_start,
                                                      csr, bias, out, N);
}

// Round 3
// 250.456 us; speedup vs baseline: 1.8770x; 1.6303x over previous
//
#include <hip/hip_runtime.h>

#define IN_DIM 128
#define HEADS 4
#define OUT_DIM 32
#define NEG 0.2f

#define NPB 256        // nodes per bucket (power of 2; bucket = dst >> 8)
#define NB_MAX 400     // max buckets (N=100000 -> 391)
#define EPB 8192       // edges per block in hist/bin kernels

typedef unsigned int uint;

__device__ __forceinline__ uint bf16r(float f) {
    uint u = __float_as_uint(f);
    return (u + 0x7fffu + ((u >> 16) & 1u)) >> 16;   // RNE
}

// ---------------- projection: feat_b(bf16) = x @ W, el/er attn dots -------
__global__ __launch_bounds__(256) void proj_kernel(
    const float* __restrict__ x, const float* __restrict__ fc_w,
    const float* __restrict__ attn_l, const float* __restrict__ attn_r,
    uint* __restrict__ feat_b, float* __restrict__ el, float* __restrict__ er,
    int N)
{
    __shared__ float xs[128 * 65];   // [i][n] transposed, padded
    const int tid = threadIdx.x;
    const int n0 = blockIdx.x * 64;

    #pragma unroll
    for (int rep = 0; rep < 32; ++rep) {
        int idx = rep * 256 + tid;
        int n = idx >> 7, i = idx & 127;
        int gn = n0 + n;
        float v = (gn < N) ? x[(size_t)gn * 128 + i] : 0.f;
        xs[i * 65 + n] = v;
    }
    __syncthreads();

    const int wave = __builtin_amdgcn_readfirstlane(tid >> 6);  // == head
    const int lane = tid & 63;
    const int k0 = wave * 32;

    float acc[32];
    #pragma unroll
    for (int d = 0; d < 32; ++d) acc[d] = 0.f;

    for (int i = 0; i < 128; ++i) {
        float xv = xs[i * 65 + lane];
        const float* wr = fc_w + i * 128 + k0;   // wave-uniform -> s_load
        #pragma unroll
        for (int d = 0; d < 32; ++d) acc[d] = fmaf(xv, wr[d], acc[d]);
    }

    const int gn = n0 + lane;
    if (gn < N) {
        uint* fp = feat_b + (size_t)gn * 64 + wave * 16;
        #pragma unroll
        for (int q = 0; q < 4; ++q) {
            uint4 v;
            v.x = bf16r(acc[q*8+0]) | (bf16r(acc[q*8+1]) << 16);
            v.y = bf16r(acc[q*8+2]) | (bf16r(acc[q*8+3]) << 16);
            v.z = bf16r(acc[q*8+4]) | (bf16r(acc[q*8+5]) << 16);
            v.w = bf16r(acc[q*8+6]) | (bf16r(acc[q*8+7]) << 16);
            *(uint4*)(fp + q * 4) = v;
        }
        float sl = 0.f, sr = 0.f;
        const float* al = attn_l + k0;
        const float* ar = attn_r + k0;
        #pragma unroll
        for (int d = 0; d < 32; ++d) {
            sl = fmaf(acc[d], al[d], sl);
            sr = fmaf(acc[d], ar[d], sr);
        }
        el[gn * 4 + wave] = sl;
        er[gn * 4 + wave] = sr;
    }
}

// ---------------- CSR build: 2-level multisplit ---------------------------
// K1: coarse bucket histogram (LDS-aggregated -> 77K global atomics total)
__global__ __launch_bounds__(256) void coarse_hist_kernel(
    const int* __restrict__ edst, int* __restrict__ bucketCount, int E, int NB)
{
    __shared__ int h[NB_MAX];
    for (int t = threadIdx.x; t < NB_MAX; t += 256) h[t] = 0;
    __syncthreads();
    const int base = blockIdx.x * EPB;
    #pragma unroll
    for (int rep = 0; rep < EPB / 1024; ++rep) {
        int i = base + (rep * 256 + threadIdx.x) * 4;
        if (i + 3 < E) {
            int4 d = *(const int4*)(edst + i);
            atomicAdd(&h[d.x >> 8], 1);
            atomicAdd(&h[d.y >> 8], 1);
            atomicAdd(&h[d.z >> 8], 1);
            atomicAdd(&h[d.w >> 8], 1);
        } else {
            for (int k = 0; k < 4; ++k)
                if (i + k < E) atomicAdd(&h[edst[i + k] >> 8], 1);
        }
    }
    __syncthreads();
    for (int t = threadIdx.x; t < NB; t += 256)
        if (h[t]) atomicAdd(&bucketCount[t], h[t]);
}

// K2: scan 391 bucket counts -> bucketStart/bucketCursor; row_start[N]=E
__global__ __launch_bounds__(512) void bucket_scan_kernel(
    const int* __restrict__ bucketCount, int* __restrict__ bucketStart,
    int* __restrict__ bucketCursor, int* __restrict__ row_start, int NB, int N)
{
    __shared__ int p[512];
    const int t = threadIdx.x;
    int v = (t < NB) ? bucketCount[t] : 0;
    p[t] = v;
    __syncthreads();
    for (int off = 1; off < 512; off <<= 1) {
        int u = (t >= off) ? p[t - off] : 0;
        __syncthreads();
        p[t] += u;
        __syncthreads();
    }
    if (t < NB) {
        bucketStart[t]  = p[t] - v;
        bucketCursor[t] = p[t] - v;
    }
    if (t == NB - 1) {
        bucketStart[NB] = p[t];
        row_start[N]    = p[t];   // == E
    }
}

// K3: bin edges into bucket-major order; payload packed (ldst<<24)|src
__global__ __launch_bounds__(256) void bin_kernel(
    const int* __restrict__ esrc, const int* __restrict__ edst,
    int* __restrict__ bucketCursor, uint* __restrict__ binned, int E, int NB)
{
    __shared__ int dstS[EPB];      // 32 KB
    __shared__ int hist[NB_MAX];
    __shared__ int cur[NB_MAX];
    const int t = threadIdx.x;
    for (int k = t; k < NB_MAX; k += 256) hist[k] = 0;
    __syncthreads();

    const int base = blockIdx.x * EPB;
    // phase 1: stage dst + LDS bucket histogram
    #pragma unroll
    for (int rep = 0; rep < EPB / 1024; ++rep) {
        int idx4 = (rep * 256 + t) * 4;
        int i = base + idx4;
        if (i + 3 < E) {
            int4 d = *(const int4*)(edst + i);
            dstS[idx4]     = d.x; atomicAdd(&hist[d.x >> 8], 1);
            dstS[idx4 + 1] = d.y; atomicAdd(&hist[d.y >> 8], 1);
            dstS[idx4 + 2] = d.z; atomicAdd(&hist[d.z >> 8], 1);
            dstS[idx4 + 3] = d.w; atomicAdd(&hist[d.w >> 8], 1);
        } else {
            for (int k = 0; k < 4; ++k)
                if (i + k < E) {
                    int dv = edst[i + k];
                    dstS[idx4 + k] = dv;
                    atomicAdd(&hist[dv >> 8], 1);
                }
        }
    }
    __syncthreads();
    // phase 2: reserve contiguous run per (block, bucket)
    for (int k = t; k < NB; k += 256) {
        int hh = hist[k];
        cur[k] = hh ? atomicAdd(&bucketCursor[k], hh) : 0;
    }
    __syncthreads();
    // phase 3: scatter into reserved runs (writes contiguous per bucket)
    const int nloc = min(EPB, E - base);
    for (int rep = 0; rep < EPB / 256; ++rep) {
        int idx = rep * 256 + t;
        if (idx < nloc) {
            int dv = dstS[idx];
            int pos = atomicAdd(&cur[dv >> 8], 1);
            int src = esrc[base + idx];                  // coalesced re-read
            binned[pos] = (uint)src | ((uint)(dv & 255) << 24);
        }
    }
}

// K4: per-bucket fine CSR: local hist -> scan -> scatter; emits row_start
__global__ __launch_bounds__(256) void fine_csr_kernel(
    const uint* __restrict__ binned, const int* __restrict__ bucketStart,
    int* __restrict__ row_start, int* __restrict__ csr, int N)
{
    __shared__ int hist[256], sc[256], cur[256];
    const int b = blockIdx.x;
    const int t = threadIdx.x;
    const int s = bucketStart[b];
    const int e = bucketStart[b + 1];

    hist[t] = 0;
    __syncthreads();
    for (int i = s + t; i < e; i += 256)
        atomicAdd(&hist[binned[i] >> 24], 1);
    __syncthreads();
    sc[t] = hist[t];
    __syncthreads();
    for (int off = 1; off < 256; off <<= 1) {
        int u = (t >= off) ? sc[t - off] : 0;
        __syncthreads();
        sc[t] += u;
        __syncthreads();
    }
    const int excl = s + sc[t] - hist[t];
    const int gn = b * NPB + t;
    if (gn < N) row_start[gn] = excl;
    cur[t] = excl;
    __syncthreads();
    for (int i = s + t; i < e; i += 256) {
        uint v = binned[i];
        int pos = atomicAdd(&cur[v >> 24], 1);
        csr[pos] = (int)(v & 0xFFFFFFu);
    }
}

// ---------------- aggregation: one wave per destination node --------------
__global__ __launch_bounds__(256) void aggregate_kernel(
    const uint* __restrict__ feat_b, const float* __restrict__ el,
    const float* __restrict__ er, const int* __restrict__ row_start,
    const int* __restrict__ csr, const float* __restrict__ bias,
    float* __restrict__ out, int N)
{
    int node = blockIdx.x * 4 + (threadIdx.x >> 6);
    node = __builtin_amdgcn_readfirstlane(node);
    if (node >= N) return;
    const int lane = threadIdx.x & 63;
    const int h = lane >> 4;

    const float er_vh = er[node * 4 + h];
    const int start = row_start[node];
    const int end   = row_start[node + 1];

    float acc0 = 0.f, acc1 = 0.f, s = 0.f;
    int u = (start < end) ? csr[start] : 0;
    for (int idx = start; idx < end; ++idx) {
        int u2 = (idx + 1 < end) ? csr[idx + 1] : 0;   // prefetch next
        float e = el[u * 4 + h] + er_vh;
        e = (e > 0.f) ? e : NEG * e;
        float ex = __expf(e);
        uint p = feat_b[(size_t)u * 64 + lane];        // 256B coalesced gather
        float lo = __uint_as_float(p << 16);
        float hi = __uint_as_float(p & 0xffff0000u);
        acc0 = fmaf(ex, lo, acc0);
        acc1 = fmaf(ex, hi, acc1);
        s += ex;
        u = u2;
    }
    s = fmaxf(s, 1e-16f);
    float r0 = acc0 / s, r1 = acc1 / s;
    r0 += __shfl_xor(r0, 16); r0 += __shfl_xor(r0, 32);
    r1 += __shfl_xor(r1, 16); r1 += __shfl_xor(r1, 32);

    if (lane < 16) {
        int d0 = lane * 2;
        float bm0 = 0.25f * (bias[d0]     + bias[32 + d0] + bias[64 + d0] + bias[96 + d0]);
        float bm1 = 0.25f * (bias[d0 + 1] + bias[33 + d0] + bias[65 + d0] + bias[97 + d0]);
        float2 o;
        o.x = 0.25f * r0 + bm0;
        o.y = 0.25f * r1 + bm1;
        ((float2*)out)[(size_t)node * 16 + lane] = o;
    }
}

// ---------------- launch --------------------------------------------------
extern "C" void kernel_launch(void* const* d_in, const int* in_sizes, int n_in,
                              void* d_out, int out_size, void* d_ws, size_t ws_size,
                              hipStream_t stream)
{
    const float* x      = (const float*)d_in[0];
    const int*   esrc   = (const int*)  d_in[1];
    const int*   edst   = (const int*)  d_in[2];
    const float* fc_w   = (const float*)d_in[3];
    const float* attn_l = (const float*)d_in[4];
    const float* attn_r = (const float*)d_in[5];
    const float* bias   = (const float*)d_in[6];
    float* out = (float*)d_out;

    const int N = in_sizes[0] / IN_DIM;   // 100000
    const int E = in_sizes[1];            // 1600000
    const int NB = (N + NPB - 1) / NPB;   // 391

    size_t o = 0;
    char* base = (char*)d_ws;
    auto alloc = [&](size_t bytes) -> void* {
        void* p = base + o;
        o += (bytes + 255) & ~(size_t)255;
        return p;
    };
    uint*  feat_b      = (uint*) alloc((size_t)N * 64 * sizeof(uint));
    float* el          = (float*)alloc((size_t)N * 4 * sizeof(float));
    float* er          = (float*)alloc((size_t)N * 4 * sizeof(float));
    int*   row_start   = (int*)  alloc(((size_t)N + 1) * sizeof(int));
    int*   csr         = (int*)  alloc((size_t)E * sizeof(int));
    uint*  binned      = (uint*) alloc((size_t)E * sizeof(uint));
    int*   bucketCount = (int*)  alloc(NB_MAX * sizeof(int));
    int*   bucketStart = (int*)  alloc((NB_MAX + 1) * sizeof(int));
    int*   bucketCursor= (int*)  alloc(NB_MAX * sizeof(int));
    (void)ws_size;

    const int nblkE = (E + EPB - 1) / EPB;   // 196

    hipMemsetAsync(bucketCount, 0, NB_MAX * sizeof(int), stream);

    proj_kernel<<<(N + 63) / 64, 256, 0, stream>>>(x, fc_w, attn_l, attn_r,
                                                   feat_b, el, er, N);
    coarse_hist_kernel<<<nblkE, 256, 0, stream>>>(edst, bucketCount, E, NB);
    bucket_scan_kernel<<<1, 512, 0, stream>>>(bucketCount, bucketStart,
                                              bucketCursor, row_start, NB, N);
    bin_kernel<<<nblkE, 256, 0, stream>>>(esrc, edst, bucketCursor, binned, E, NB);
    fine_csr_kernel<<<NB, 256, 0, stream>>>(binned, bucketStart, row_start, csr, N);
    aggregate_kernel<<<(N + 3) / 4, 256, 0, stream>>>(feat_b, el, er, row_start,
                                                      csr, bias, out, N);
}

// Round 4
// 205.134 us; speedup vs baseline: 2.2917x; 1.2209x over previous
//
#include <hip/hip_runtime.h>

#define IN_DIM 128
#define HEADS 4
#define OUT_DIM 32
#define NEG 0.2f

#define NPB 256        // nodes per bucket (power of 2; bucket = dst >> 8)
#define NB_MAX 400     // max buckets (N=100000 -> 391)
#define EPB 8192       // edges per block in hist/bin kernels

typedef unsigned int uint;

__device__ __forceinline__ uint bf16r(float f) {
    uint u = __float_as_uint(f);
    return (u + 0x7fffu + ((u >> 16) & 1u)) >> 16;   // RNE
}

// ---------------- projection: feat_b(bf16) = x @ W, el/er attn dots -------
__global__ __launch_bounds__(256) void proj_kernel(
    const float* __restrict__ x, const float* __restrict__ fc_w,
    const float* __restrict__ attn_l, const float* __restrict__ attn_r,
    uint* __restrict__ feat_b, float* __restrict__ el, float* __restrict__ er,
    int N)
{
    __shared__ float xs[128 * 65];   // [i][n] transposed, padded
    const int tid = threadIdx.x;
    const int n0 = blockIdx.x * 64;

    #pragma unroll
    for (int rep = 0; rep < 32; ++rep) {
        int idx = rep * 256 + tid;
        int n = idx >> 7, i = idx & 127;
        int gn = n0 + n;
        float v = (gn < N) ? x[(size_t)gn * 128 + i] : 0.f;
        xs[i * 65 + n] = v;
    }
    __syncthreads();

    const int wave = __builtin_amdgcn_readfirstlane(tid >> 6);  // == head
    const int lane = tid & 63;
    const int k0 = wave * 32;

    float acc[32];
    #pragma unroll
    for (int d = 0; d < 32; ++d) acc[d] = 0.f;

    for (int i = 0; i < 128; ++i) {
        float xv = xs[i * 65 + lane];
        const float* wr = fc_w + i * 128 + k0;   // wave-uniform -> s_load
        #pragma unroll
        for (int d = 0; d < 32; ++d) acc[d] = fmaf(xv, wr[d], acc[d]);
    }

    const int gn = n0 + lane;
    if (gn < N) {
        uint* fp = feat_b + (size_t)gn * 64 + wave * 16;
        #pragma unroll
        for (int q = 0; q < 4; ++q) {
            uint4 v;
            v.x = bf16r(acc[q*8+0]) | (bf16r(acc[q*8+1]) << 16);
            v.y = bf16r(acc[q*8+2]) | (bf16r(acc[q*8+3]) << 16);
            v.z = bf16r(acc[q*8+4]) | (bf16r(acc[q*8+5]) << 16);
            v.w = bf16r(acc[q*8+6]) | (bf16r(acc[q*8+7]) << 16);
            *(uint4*)(fp + q * 4) = v;
        }
        float sl = 0.f, sr = 0.f;
        const float* al = attn_l + k0;
        const float* ar = attn_r + k0;
        #pragma unroll
        for (int d = 0; d < 32; ++d) {
            sl = fmaf(acc[d], al[d], sl);
            sr = fmaf(acc[d], ar[d], sr);
        }
        el[gn * 4 + wave] = sl;
        er[gn * 4 + wave] = sr;
    }
}

// ---------------- CSR build: 2-level multisplit ---------------------------
__global__ __launch_bounds__(256) void coarse_hist_kernel(
    const int* __restrict__ edst, int* __restrict__ bucketCount, int E, int NB)
{
    __shared__ int h[NB_MAX];
    for (int t = threadIdx.x; t < NB_MAX; t += 256) h[t] = 0;
    __syncthreads();
    const int base = blockIdx.x * EPB;
    #pragma unroll
    for (int rep = 0; rep < EPB / 1024; ++rep) {
        int i = base + (rep * 256 + threadIdx.x) * 4;
        if (i + 3 < E) {
            int4 d = *(const int4*)(edst + i);
            atomicAdd(&h[d.x >> 8], 1);
            atomicAdd(&h[d.y >> 8], 1);
            atomicAdd(&h[d.z >> 8], 1);
            atomicAdd(&h[d.w >> 8], 1);
        } else {
            for (int k = 0; k < 4; ++k)
                if (i + k < E) atomicAdd(&h[edst[i + k] >> 8], 1);
        }
    }
    __syncthreads();
    for (int t = threadIdx.x; t < NB; t += 256)
        if (h[t]) atomicAdd(&bucketCount[t], h[t]);
}

__global__ __launch_bounds__(512) void bucket_scan_kernel(
    const int* __restrict__ bucketCount, int* __restrict__ bucketStart,
    int* __restrict__ bucketCursor, int* __restrict__ row_start, int NB, int N)
{
    __shared__ int p[512];
    const int t = threadIdx.x;
    int v = (t < NB) ? bucketCount[t] : 0;
    p[t] = v;
    __syncthreads();
    for (int off = 1; off < 512; off <<= 1) {
        int u = (t >= off) ? p[t - off] : 0;
        __syncthreads();
        p[t] += u;
        __syncthreads();
    }
    if (t < NB) {
        bucketStart[t]  = p[t] - v;
        bucketCursor[t] = p[t] - v;
    }
    if (t == NB - 1) {
        bucketStart[NB] = p[t];
        row_start[N]    = p[t];   // == E
    }
}

__global__ __launch_bounds__(256) void bin_kernel(
    const int* __restrict__ esrc, const int* __restrict__ edst,
    int* __restrict__ bucketCursor, uint* __restrict__ binned, int E, int NB)
{
    __shared__ int dstS[EPB];      // 32 KB
    __shared__ int hist[NB_MAX];
    __shared__ int cur[NB_MAX];
    const int t = threadIdx.x;
    for (int k = t; k < NB_MAX; k += 256) hist[k] = 0;
    __syncthreads();

    const int base = blockIdx.x * EPB;
    #pragma unroll
    for (int rep = 0; rep < EPB / 1024; ++rep) {
        int idx4 = (rep * 256 + t) * 4;
        int i = base + idx4;
        if (i + 3 < E) {
            int4 d = *(const int4*)(edst + i);
            dstS[idx4]     = d.x; atomicAdd(&hist[d.x >> 8], 1);
            dstS[idx4 + 1] = d.y; atomicAdd(&hist[d.y >> 8], 1);
            dstS[idx4 + 2] = d.z; atomicAdd(&hist[d.z >> 8], 1);
            dstS[idx4 + 3] = d.w; atomicAdd(&hist[d.w >> 8], 1);
        } else {
            for (int k = 0; k < 4; ++k)
                if (i + k < E) {
                    int dv = edst[i + k];
                    dstS[idx4 + k] = dv;
                    atomicAdd(&hist[dv >> 8], 1);
                }
        }
    }
    __syncthreads();
    for (int k = t; k < NB; k += 256) {
        int hh = hist[k];
        cur[k] = hh ? atomicAdd(&bucketCursor[k], hh) : 0;
    }
    __syncthreads();
    const int nloc = min(EPB, E - base);
    for (int rep = 0; rep < EPB / 256; ++rep) {
        int idx = rep * 256 + t;
        if (idx < nloc) {
            int dv = dstS[idx];
            int pos = atomicAdd(&cur[dv >> 8], 1);
            int src = esrc[base + idx];                  // coalesced re-read
            binned[pos] = (uint)src | ((uint)(dv & 255) << 24);
        }
    }
}

__global__ __launch_bounds__(256) void fine_csr_kernel(
    const uint* __restrict__ binned, const int* __restrict__ bucketStart,
    int* __restrict__ row_start, int* __restrict__ csr, int N)
{
    __shared__ int hist[256], sc[256], cur[256];
    const int b = blockIdx.x;
    const int t = threadIdx.x;
    const int s = bucketStart[b];
    const int e = bucketStart[b + 1];

    hist[t] = 0;
    __syncthreads();
    for (int i = s + t; i < e; i += 256)
        atomicAdd(&hist[binned[i] >> 24], 1);
    __syncthreads();
    sc[t] = hist[t];
    __syncthreads();
    for (int off = 1; off < 256; off <<= 1) {
        int u = (t >= off) ? sc[t - off] : 0;
        __syncthreads();
        sc[t] += u;
        __syncthreads();
    }
    const int excl = s + sc[t] - hist[t];
    const int gn = b * NPB + t;
    if (gn < N) row_start[gn] = excl;
    cur[t] = excl;
    __syncthreads();
    for (int i = s + t; i < e; i += 256) {
        uint v = binned[i];
        int pos = atomicAdd(&cur[v >> 24], 1);
        csr[pos] = (int)(v & 0xFFFFFFu);
    }
}

// ---------------- aggregation: one wave per destination node --------------
// 4-deep unrolled edge loop with independent accumulator chains -> ~8
// outstanding gathers per wave (was ~2; latency-bound per round-3 evidence:
// halving gather bytes didn't change time, so time ~ #memory-ops).
__global__ __launch_bounds__(256) void aggregate_kernel(
    const uint* __restrict__ feat_b, const float* __restrict__ el,
    const float* __restrict__ er, const int* __restrict__ row_start,
    const int* __restrict__ csr, const float* __restrict__ bias,
    float* __restrict__ out, int N)
{
    int node = blockIdx.x * 4 + (threadIdx.x >> 6);
    node = __builtin_amdgcn_readfirstlane(node);
    if (node >= N) return;
    const int lane = threadIdx.x & 63;
    const int h = lane >> 4;

    const float er_vh = er[node * 4 + h];
    const int start = row_start[node];
    const int end   = row_start[node + 1];

    float a0 = 0.f, a1 = 0.f, sa = 0.f;
    float b0 = 0.f, b1 = 0.f, sb = 0.f;
    float c0 = 0.f, c1 = 0.f, sc = 0.f;
    float d0 = 0.f, d1 = 0.f, sd = 0.f;

    int idx = start;
    for (; idx + 4 <= end; idx += 4) {
        // wave-uniform consecutive dwords -> s_load_dwordx4
        int u0 = csr[idx + 0];
        int u1 = csr[idx + 1];
        int u2 = csr[idx + 2];
        int u3 = csr[idx + 3];
        // 8 independent gathers in flight
        float e0 = el[u0 * 4 + h];
        float e1 = el[u1 * 4 + h];
        float e2 = el[u2 * 4 + h];
        float e3 = el[u3 * 4 + h];
        uint p0 = feat_b[(size_t)u0 * 64 + lane];
        uint p1 = feat_b[(size_t)u1 * 64 + lane];
        uint p2 = feat_b[(size_t)u2 * 64 + lane];
        uint p3 = feat_b[(size_t)u3 * 64 + lane];

        e0 += er_vh; e0 = fmaxf(e0, NEG * e0); float x0 = __expf(e0);
        e1 += er_vh; e1 = fmaxf(e1, NEG * e1); float x1 = __expf(e1);
        e2 += er_vh; e2 = fmaxf(e2, NEG * e2); float x2 = __expf(e2);
        e3 += er_vh; e3 = fmaxf(e3, NEG * e3); float x3 = __expf(e3);

        a0 = fmaf(x0, __uint_as_float(p0 << 16), a0);
        a1 = fmaf(x0, __uint_as_float(p0 & 0xffff0000u), a1);
        sa += x0;
        b0 = fmaf(x1, __uint_as_float(p1 << 16), b0);
        b1 = fmaf(x1, __uint_as_float(p1 & 0xffff0000u), b1);
        sb += x1;
        c0 = fmaf(x2, __uint_as_float(p2 << 16), c0);
        c1 = fmaf(x2, __uint_as_float(p2 & 0xffff0000u), c1);
        sc += x2;
        d0 = fmaf(x3, __uint_as_float(p3 << 16), d0);
        d1 = fmaf(x3, __uint_as_float(p3 & 0xffff0000u), d1);
        sd += x3;
    }
    for (; idx < end; ++idx) {          // tail (<=3)
        int u = csr[idx];
        float e = el[u * 4 + h] + er_vh;
        e = fmaxf(e, NEG * e);
        float ex = __expf(e);
        uint p = feat_b[(size_t)u * 64 + lane];
        a0 = fmaf(ex, __uint_as_float(p << 16), a0);
        a1 = fmaf(ex, __uint_as_float(p & 0xffff0000u), a1);
        sa += ex;
    }

    float s = (sa + sb) + (sc + sd);
    s = fmaxf(s, 1e-16f);
    float r0 = ((a0 + b0) + (c0 + d0)) / s;
    float r1 = ((a1 + b1) + (c1 + d1)) / s;
    r0 += __shfl_xor(r0, 16); r0 += __shfl_xor(r0, 32);
    r1 += __shfl_xor(r1, 16); r1 += __shfl_xor(r1, 32);

    if (lane < 16) {
        int dd = lane * 2;
        float bm0 = 0.25f * (bias[dd]     + bias[32 + dd] + bias[64 + dd] + bias[96 + dd]);
        float bm1 = 0.25f * (bias[dd + 1] + bias[33 + dd] + bias[65 + dd] + bias[97 + dd]);
        float2 o;
        o.x = 0.25f * r0 + bm0;
        o.y = 0.25f * r1 + bm1;
        ((float2*)out)[(size_t)node * 16 + lane] = o;
    }
}

// ---------------- launch --------------------------------------------------
extern "C" void kernel_launch(void* const* d_in, const int* in_sizes, int n_in,
                              void* d_out, int out_size, void* d_ws, size_t ws_size,
                              hipStream_t stream)
{
    const float* x      = (const float*)d_in[0];
    const int*   esrc   = (const int*)  d_in[1];
    const int*   edst   = (const int*)  d_in[2];
    const float* fc_w   = (const float*)d_in[3];
    const float* attn_l = (const float*)d_in[4];
    const float* attn_r = (const float*)d_in[5];
    const float* bias   = (const float*)d_in[6];
    float* out = (float*)d_out;

    const int N = in_sizes[0] / IN_DIM;   // 100000
    const int E = in_sizes[1];            // 1600000
    const int NB = (N + NPB - 1) / NPB;   // 391

    size_t o = 0;
    char* base = (char*)d_ws;
    auto alloc = [&](size_t bytes) -> void* {
        void* p = base + o;
        o += (bytes + 255) & ~(size_t)255;
        return p;
    };
    uint*  feat_b      = (uint*) alloc((size_t)N * 64 * sizeof(uint));
    float* el          = (float*)alloc((size_t)N * 4 * sizeof(float));
    float* er          = (float*)alloc((size_t)N * 4 * sizeof(float));
    int*   row_start   = (int*)  alloc(((size_t)N + 1) * sizeof(int));
    int*   csr         = (int*)  alloc((size_t)E * sizeof(int));
    uint*  binned      = (uint*) alloc((size_t)E * sizeof(uint));
    int*   bucketCount = (int*)  alloc(NB_MAX * sizeof(int));
    int*   bucketStart = (int*)  alloc((NB_MAX + 1) * sizeof(int));
    int*   bucketCursor= (int*)  alloc(NB_MAX * sizeof(int));
    (void)ws_size;

    const int nblkE = (E + EPB - 1) / EPB;   // 196

    hipMemsetAsync(bucketCount, 0, NB_MAX * sizeof(int), stream);

    proj_kernel<<<(N + 63) / 64, 256, 0, stream>>>(x, fc_w, attn_l, attn_r,
                                                   feat_b, el, er, N);
    coarse_hist_kernel<<<nblkE, 256, 0, stream>>>(edst, bucketCount, E, NB);
    bucket_scan_kernel<<<1, 512, 0, stream>>>(bucketCount, bucketStart,
                                              bucketCursor, row_start, NB, N);
    bin_kernel<<<nblkE, 256, 0, stream>>>(esrc, edst, bucketCursor, binned, E, NB);
    fine_csr_kernel<<<NB, 256, 0, stream>>>(binned, bucketStart, row_start, csr, N);
    aggregate_kernel<<<(N + 3) / 4, 256, 0, stream>>>(feat_b, el, er, row_start,
                                                      csr, bias, out, N);
}

// Round 5
// 168.647 us; speedup vs baseline: 2.7876x; 1.2164x over previous
//
#include <hip/hip_runtime.h>

#define IN_DIM 128
#define HEADS 4
#define OUT_DIM 32
#define NEG 0.2f

#define NPB 256        // nodes per bucket (power of 2; bucket = dst >> 8)
#define NB_MAX 400     // max buckets (N=100000 -> 391)
#define EPB 8192       // edges per block in hist/bin kernels

typedef unsigned int uint;
typedef unsigned short ushort_t;
typedef short short8 __attribute__((ext_vector_type(8)));
typedef float f32x4 __attribute__((ext_vector_type(4)));
typedef uint u32x4 __attribute__((ext_vector_type(4)));

__device__ __forceinline__ uint bf16r(float f) {
    uint u = __float_as_uint(f);
    return (u + 0x7fffu + ((u >> 16) & 1u)) >> 16;   // RNE
}

// ---------------- W^T bf16 prep: wt[n][k] = bf16(W[k][n]) -----------------
__global__ __launch_bounds__(256) void wt_prep_kernel(
    const float* __restrict__ fc_w, ushort_t* __restrict__ wt)
{
    int t = blockIdx.x * 256 + threadIdx.x;   // 64 blocks x 256 = 16384
    int n = t >> 7, k = t & 127;
    wt[t] = (ushort_t)bf16r(fc_w[k * 128 + n]);
}

// ---------------- projection via MFMA (no LDS) ----------------------------
// Block=256=4 waves; wave w: rows [b*64+16w, +16) x all 128 cols.
// A-frag: lane row=lane&15, k=(lane>>4)*8+j (8 f32 from x, cvt->bf16).
// B-frag: direct dwordx4 from wt[n][k] (L2-hot 32KB).
// D: col=lane&15, row=(lane>>4)*4+reg  [m89-verified mapping].
// Epilogue: feat16 stores + el/er from f32 acc via 16-lane shfl reduce.
__global__ __launch_bounds__(256) void proj_kernel(
    const float* __restrict__ x, const ushort_t* __restrict__ wt,
    const float* __restrict__ attn_l, const float* __restrict__ attn_r,
    ushort_t* __restrict__ feat16, float* __restrict__ el, float* __restrict__ er,
    int N)
{
    const int lane = threadIdx.x & 63;
    const int w    = threadIdx.x >> 6;
    const int rowbase = blockIdx.x * 64 + w * 16;
    const int c = lane & 15;
    const int g = lane >> 4;

    f32x4 acc[8];
    #pragma unroll
    for (int nt = 0; nt < 8; ++nt) acc[nt] = (f32x4){0.f, 0.f, 0.f, 0.f};

    const int arow  = rowbase + c;
    const int arowc = (arow < N) ? arow : (N - 1);     // clamp OOB reads
    const float* xrow = x + (size_t)arowc * 128 + g * 8;

    #pragma unroll
    for (int kk = 0; kk < 4; ++kk) {
        const float* xp = xrow + kk * 32;
        float4 f0 = *(const float4*)xp;
        float4 f1 = *(const float4*)(xp + 4);
        u32x4 au;
        au.x = bf16r(f0.x) | (bf16r(f0.y) << 16);
        au.y = bf16r(f0.z) | (bf16r(f0.w) << 16);
        au.z = bf16r(f1.x) | (bf16r(f1.y) << 16);
        au.w = bf16r(f1.z) | (bf16r(f1.w) << 16);
        short8 afrag = __builtin_bit_cast(short8, au);
        #pragma unroll
        for (int nt = 0; nt < 8; ++nt) {
            const ushort_t* wp = wt + ((nt * 16 + c) * 128 + kk * 32 + g * 8);
            u32x4 bu = *(const u32x4*)wp;               // 16B aligned
            short8 bfrag = __builtin_bit_cast(short8, bu);
            acc[nt] = __builtin_amdgcn_mfma_f32_16x16x32_bf16(afrag, bfrag, acc[nt], 0, 0, 0);
        }
    }

    // per-lane attn slices: head h cols [32h+c, 32h+16+c]
    float alv[4][2], arv[4][2];
    #pragma unroll
    for (int h = 0; h < 4; ++h) {
        alv[h][0] = attn_l[h * 32 + c];
        alv[h][1] = attn_l[h * 32 + 16 + c];
        arv[h][0] = attn_r[h * 32 + c];
        arv[h][1] = attn_r[h * 32 + 16 + c];
    }

    #pragma unroll
    for (int r = 0; r < 4; ++r) {
        const int node = rowbase + g * 4 + r;   // uniform across the 16 c-lanes
        const bool ok = (node < N);
        ushort_t* fp = feat16 + (size_t)node * 128 + c;
        #pragma unroll
        for (int nt = 0; nt < 8; ++nt) {
            if (ok) fp[nt * 16] = (ushort_t)bf16r(acc[nt][r]);
        }
        #pragma unroll
        for (int h = 0; h < 4; ++h) {
            float accl = acc[2*h][r] * alv[h][0] + acc[2*h+1][r] * alv[h][1];
            float accr = acc[2*h][r] * arv[h][0] + acc[2*h+1][r] * arv[h][1];
            accl += __shfl_xor(accl, 1); accl += __shfl_xor(accl, 2);
            accl += __shfl_xor(accl, 4); accl += __shfl_xor(accl, 8);
            accr += __shfl_xor(accr, 1); accr += __shfl_xor(accr, 2);
            accr += __shfl_xor(accr, 4); accr += __shfl_xor(accr, 8);
            if (ok && c == 0) {
                el[node * 4 + h] = accl;
                er[node * 4 + h] = accr;
            }
        }
    }
}

// ---------------- CSR build: 2-level multisplit ---------------------------
__global__ __launch_bounds__(256) void coarse_hist_kernel(
    const int* __restrict__ edst, int* __restrict__ bucketCount, int E, int NB)
{
    __shared__ int h[NB_MAX];
    for (int t = threadIdx.x; t < NB_MAX; t += 256) h[t] = 0;
    __syncthreads();
    const int base = blockIdx.x * EPB;
    #pragma unroll
    for (int rep = 0; rep < EPB / 1024; ++rep) {
        int i = base + (rep * 256 + threadIdx.x) * 4;
        if (i + 3 < E) {
            int4 d = *(const int4*)(edst + i);
            atomicAdd(&h[d.x >> 8], 1);
            atomicAdd(&h[d.y >> 8], 1);
            atomicAdd(&h[d.z >> 8], 1);
            atomicAdd(&h[d.w >> 8], 1);
        } else {
            for (int k = 0; k < 4; ++k)
                if (i + k < E) atomicAdd(&h[edst[i + k] >> 8], 1);
        }
    }
    __syncthreads();
    for (int t = threadIdx.x; t < NB; t += 256)
        if (h[t]) atomicAdd(&bucketCount[t], h[t]);
}

__global__ __launch_bounds__(512) void bucket_scan_kernel(
    const int* __restrict__ bucketCount, int* __restrict__ bucketStart,
    int* __restrict__ bucketCursor, int* __restrict__ row_start, int NB, int N)
{
    __shared__ int p[512];
    const int t = threadIdx.x;
    int v = (t < NB) ? bucketCount[t] : 0;
    p[t] = v;
    __syncthreads();
    for (int off = 1; off < 512; off <<= 1) {
        int u = (t >= off) ? p[t - off] : 0;
        __syncthreads();
        p[t] += u;
        __syncthreads();
    }
    if (t < NB) {
        bucketStart[t]  = p[t] - v;
        bucketCursor[t] = p[t] - v;
    }
    if (t == NB - 1) {
        bucketStart[NB] = p[t];
        row_start[N]    = p[t];   // == E
    }
}

__global__ __launch_bounds__(256) void bin_kernel(
    const int* __restrict__ esrc, const int* __restrict__ edst,
    int* __restrict__ bucketCursor, uint* __restrict__ binned, int E, int NB)
{
    __shared__ int dstS[EPB];      // 32 KB
    __shared__ int hist[NB_MAX];
    __shared__ int cur[NB_MAX];
    const int t = threadIdx.x;
    for (int k = t; k < NB_MAX; k += 256) hist[k] = 0;
    __syncthreads();

    const int base = blockIdx.x * EPB;
    #pragma unroll
    for (int rep = 0; rep < EPB / 1024; ++rep) {
        int idx4 = (rep * 256 + t) * 4;
        int i = base + idx4;
        if (i + 3 < E) {
            int4 d = *(const int4*)(edst + i);
            dstS[idx4]     = d.x; atomicAdd(&hist[d.x >> 8], 1);
            dstS[idx4 + 1] = d.y; atomicAdd(&hist[d.y >> 8], 1);
            dstS[idx4 + 2] = d.z; atomicAdd(&hist[d.z >> 8], 1);
            dstS[idx4 + 3] = d.w; atomicAdd(&hist[d.w >> 8], 1);
        } else {
            for (int k = 0; k < 4; ++k)
                if (i + k < E) {
                    int dv = edst[i + k];
                    dstS[idx4 + k] = dv;
                    atomicAdd(&hist[dv >> 8], 1);
                }
        }
    }
    __syncthreads();
    for (int k = t; k < NB; k += 256) {
        int hh = hist[k];
        cur[k] = hh ? atomicAdd(&bucketCursor[k], hh) : 0;
    }
    __syncthreads();
    const int nloc = min(EPB, E - base);
    for (int rep = 0; rep < EPB / 256; ++rep) {
        int idx = rep * 256 + t;
        if (idx < nloc) {
            int dv = dstS[idx];
            int pos = atomicAdd(&cur[dv >> 8], 1);
            int src = esrc[base + idx];                  // coalesced re-read
            binned[pos] = (uint)src | ((uint)(dv & 255) << 24);
        }
    }
}

__global__ __launch_bounds__(256) void fine_csr_kernel(
    const uint* __restrict__ binned, const int* __restrict__ bucketStart,
    int* __restrict__ row_start, int* __restrict__ csr, int N)
{
    __shared__ int hist[256], sc[256], cur[256];
    const int b = blockIdx.x;
    const int t = threadIdx.x;
    const int s = bucketStart[b];
    const int e = bucketStart[b + 1];

    hist[t] = 0;
    __syncthreads();
    for (int i = s + t; i < e; i += 256)
        atomicAdd(&hist[binned[i] >> 24], 1);
    __syncthreads();
    sc[t] = hist[t];
    __syncthreads();
    for (int off = 1; off < 256; off <<= 1) {
        int u = (t >= off) ? sc[t - off] : 0;
        __syncthreads();
        sc[t] += u;
        __syncthreads();
    }
    const int excl = s + sc[t] - hist[t];
    const int gn = b * NPB + t;
    if (gn < N) row_start[gn] = excl;
    cur[t] = excl;
    __syncthreads();
    for (int i = s + t; i < e; i += 256) {
        uint v = binned[i];
        int pos = atomicAdd(&cur[v >> 24], 1);
        csr[pos] = (int)(v & 0xFFFFFFu);
    }
}

// ---------------- aggregation: one wave per destination node --------------
__global__ __launch_bounds__(256) void aggregate_kernel(
    const uint* __restrict__ feat_b, const float* __restrict__ el,
    const float* __restrict__ er, const int* __restrict__ row_start,
    const int* __restrict__ csr, const float* __restrict__ bias,
    float* __restrict__ out, int N)
{
    int node = blockIdx.x * 4 + (threadIdx.x >> 6);
    node = __builtin_amdgcn_readfirstlane(node);
    if (node >= N) return;
    const int lane = threadIdx.x & 63;
    const int h = lane >> 4;

    const float er_vh = er[node * 4 + h];
    const int start = row_start[node];
    const int end   = row_start[node + 1];

    float a0 = 0.f, a1 = 0.f, sa = 0.f;
    float b0 = 0.f, b1 = 0.f, sb = 0.f;
    float c0 = 0.f, c1 = 0.f, sc = 0.f;
    float d0 = 0.f, d1 = 0.f, sd = 0.f;

    int idx = start;
    for (; idx + 4 <= end; idx += 4) {
        int u0 = csr[idx + 0];
        int u1 = csr[idx + 1];
        int u2 = csr[idx + 2];
        int u3 = csr[idx + 3];
        float e0 = el[u0 * 4 + h];
        float e1 = el[u1 * 4 + h];
        float e2 = el[u2 * 4 + h];
        float e3 = el[u3 * 4 + h];
        uint p0 = feat_b[(size_t)u0 * 64 + lane];
        uint p1 = feat_b[(size_t)u1 * 64 + lane];
        uint p2 = feat_b[(size_t)u2 * 64 + lane];
        uint p3 = feat_b[(size_t)u3 * 64 + lane];

        e0 += er_vh; e0 = fmaxf(e0, NEG * e0); float x0 = __expf(e0);
        e1 += er_vh; e1 = fmaxf(e1, NEG * e1); float x1 = __expf(e1);
        e2 += er_vh; e2 = fmaxf(e2, NEG * e2); float x2 = __expf(e2);
        e3 += er_vh; e3 = fmaxf(e3, NEG * e3); float x3 = __expf(e3);

        a0 = fmaf(x0, __uint_as_float(p0 << 16), a0);
        a1 = fmaf(x0, __uint_as_float(p0 & 0xffff0000u), a1);
        sa += x0;
        b0 = fmaf(x1, __uint_as_float(p1 << 16), b0);
        b1 = fmaf(x1, __uint_as_float(p1 & 0xffff0000u), b1);
        sb += x1;
        c0 = fmaf(x2, __uint_as_float(p2 << 16), c0);
        c1 = fmaf(x2, __uint_as_float(p2 & 0xffff0000u), c1);
        sc += x2;
        d0 = fmaf(x3, __uint_as_float(p3 << 16), d0);
        d1 = fmaf(x3, __uint_as_float(p3 & 0xffff0000u), d1);
        sd += x3;
    }
    for (; idx < end; ++idx) {
        int u = csr[idx];
        float e = el[u * 4 + h] + er_vh;
        e = fmaxf(e, NEG * e);
        float ex = __expf(e);
        uint p = feat_b[(size_t)u * 64 + lane];
        a0 = fmaf(ex, __uint_as_float(p << 16), a0);
        a1 = fmaf(ex, __uint_as_float(p & 0xffff0000u), a1);
        sa += ex;
    }

    float s = (sa + sb) + (sc + sd);
    s = fmaxf(s, 1e-16f);
    float r0 = ((a0 + b0) + (c0 + d0)) / s;
    float r1 = ((a1 + b1) + (c1 + d1)) / s;
    r0 += __shfl_xor(r0, 16); r0 += __shfl_xor(r0, 32);
    r1 += __shfl_xor(r1, 16); r1 += __shfl_xor(r1, 32);

    if (lane < 16) {
        int dd = lane * 2;
        float bm0 = 0.25f * (bias[dd]     + bias[32 + dd] + bias[64 + dd] + bias[96 + dd]);
        float bm1 = 0.25f * (bias[dd + 1] + bias[33 + dd] + bias[65 + dd] + bias[97 + dd]);
        float2 o;
        o.x = 0.25f * r0 + bm0;
        o.y = 0.25f * r1 + bm1;
        ((float2*)out)[(size_t)node * 16 + lane] = o;
    }
}

// ---------------- launch --------------------------------------------------
extern "C" void kernel_launch(void* const* d_in, const int* in_sizes, int n_in,
                              void* d_out, int out_size, void* d_ws, size_t ws_size,
                              hipStream_t stream)
{
    const float* x      = (const float*)d_in[0];
    const int*   esrc   = (const int*)  d_in[1];
    const int*   edst   = (const int*)  d_in[2];
    const float* fc_w   = (const float*)d_in[3];
    const float* attn_l = (const float*)d_in[4];
    const float* attn_r = (const float*)d_in[5];
    const float* bias   = (const float*)d_in[6];
    float* out = (float*)d_out;

    const int N = in_sizes[0] / IN_DIM;   // 100000
    const int E = in_sizes[1];            // 1600000
    const int NB = (N + NPB - 1) / NPB;   // 391

    size_t o = 0;
    char* base = (char*)d_ws;
    auto alloc = [&](size_t bytes) -> void* {
        void* p = base + o;
        o += (bytes + 255) & ~(size_t)255;
        return p;
    };
    ushort_t* feat16   = (ushort_t*)alloc((size_t)N * 128 * sizeof(ushort_t));
    float* el          = (float*)alloc((size_t)N * 4 * sizeof(float));
    float* er          = (float*)alloc((size_t)N * 4 * sizeof(float));
    int*   row_start   = (int*)  alloc(((size_t)N + 1) * sizeof(int));
    int*   csr         = (int*)  alloc((size_t)E * sizeof(int));
    uint*  binned      = (uint*) alloc((size_t)E * sizeof(uint));
    int*   bucketCount = (int*)  alloc(NB_MAX * sizeof(int));
    int*   bucketStart = (int*)  alloc((NB_MAX + 1) * sizeof(int));
    int*   bucketCursor= (int*)  alloc(NB_MAX * sizeof(int));
    ushort_t* wt       = (ushort_t*)alloc((size_t)128 * 128 * sizeof(ushort_t));
    (void)ws_size;

    const int nblkE = (E + EPB - 1) / EPB;   // 196

    hipMemsetAsync(bucketCount, 0, NB_MAX * sizeof(int), stream);

    wt_prep_kernel<<<64, 256, 0, stream>>>(fc_w, wt);
    proj_kernel<<<(N + 63) / 64, 256, 0, stream>>>(x, wt, attn_l, attn_r,
                                                   feat16, el, er, N);
    coarse_hist_kernel<<<nblkE, 256, 0, stream>>>(edst, bucketCount, E, NB);
    bucket_scan_kernel<<<1, 512, 0, stream>>>(bucketCount, bucketStart,
                                              bucketCursor, row_start, NB, N);
    bin_kernel<<<nblkE, 256, 0, stream>>>(esrc, edst, bucketCursor, binned, E, NB);
    fine_csr_kernel<<<NB, 256, 0, stream>>>(binned, bucketStart, row_start, csr, N);
    aggregate_kernel<<<(N + 3) / 4, 256, 0, stream>>>((const uint*)feat16, el, er,
                                                      row_start, csr, bias, out, N);
}